// Round 5
// baseline (316.385 us; speedup 1.0000x reference)
//
#include <hip/hip_runtime.h>

#define BLK 256
#define PSH 11
#define PART 2048          // nodes per dst-bucket (2nd-level sort granularity)
#define G1 1024            // blocks in hist/partition passes
#define MAXB 128           // max buckets (LDS counters in 1st-level kernels)
#define KB 8               // per-bucket edge slices (parallelism of 2nd level)

// ---------------- helpers ----------------

__device__ __forceinline__ int edge_at(const void* idx, int is64, long long pos) {
  return is64 ? (int)((const long long*)idx)[pos] : ((const int*)idx)[pos];
}

// Detect int64 vs int32 storage: for int64 values < 2^31 the odd 32-bit words are 0.
__global__ void k_detect(const unsigned* __restrict__ w, int* __restrict__ flag) {
  __shared__ int any;
  if (threadIdx.x == 0) any = 0;
  __syncthreads();
  if (w[2 * threadIdx.x + 1] != 0u) atomicOr(&any, 1);
  __syncthreads();
  if (threadIdx.x == 0) *flag = (any == 0) ? 1 : 0;  // 1 => int64
}

// ---------------- CSR-building path ----------------

// 1st level: per-block histogram of dst buckets; hist layout [bucket][block]
__global__ __launch_bounds__(BLK) void k_hist(const void* __restrict__ ei,
                                              const int* __restrict__ flag,
                                              int E, int chunk, int NB,
                                              int* __restrict__ hist) {
  __shared__ int cnt[MAXB];
  for (int j = threadIdx.x; j < NB; j += BLK) cnt[j] = 0;
  __syncthreads();
  int is64 = *flag;
  int beg = blockIdx.x * chunk, end = min(E, beg + chunk);
  for (int i = beg + threadIdx.x; i < end; i += BLK) {
    int d = edge_at(ei, is64, (long long)E + i);
    atomicAdd(&cnt[d >> PSH], 1);
  }
  __syncthreads();
  for (int j = threadIdx.x; j < NB; j += BLK) hist[(size_t)j * G1 + blockIdx.x] = cnt[j];
}

// scan per-(bucket,block) offsets IN PLACE over hist; bucket starts -> ebstart
__global__ void k_scan(int* __restrict__ hist, int NB, int* __restrict__ ebstart) {
  __shared__ int tot[MAXB];
  int b = threadIdx.x;
  if (b < NB) {
    int run = 0;
    int* h = hist + (size_t)b * G1;
    for (int i = 0; i < G1; ++i) { int tmp = h[i]; h[i] = run; run += tmp; }
    tot[b] = run;
  }
  __syncthreads();
  if (threadIdx.x == 0) {
    int run = 0;
    for (int j = 0; j < NB; ++j) { ebstart[j] = run; run += tot[j]; }
    ebstart[NB] = run;
  }
}

// partition: write packed (src<<PSH | dst_local) into bucket-ordered array
__global__ __launch_bounds__(BLK) void k_part(const void* __restrict__ ei,
                                              const int* __restrict__ flag,
                                              int E, int chunk, int NB,
                                              const int* __restrict__ offs,
                                              const int* __restrict__ ebstart,
                                              int* __restrict__ packed) {
  __shared__ int cnt[MAXB];
  int t = threadIdx.x;
  if (t < NB) cnt[t] = ebstart[t] + offs[(size_t)t * G1 + blockIdx.x];
  __syncthreads();
  int is64 = *flag;
  int beg = blockIdx.x * chunk, end = min(E, beg + chunk);
  for (int i = beg + t; i < end; i += BLK) {
    int s = edge_at(ei, is64, i);
    int d = edge_at(ei, is64, (long long)E + i);
    int pos = atomicAdd(&cnt[d >> PSH], 1);
    packed[pos] = (s << PSH) | (d & (PART - 1));
  }
}

// 2nd level: per-(bucket,slice) dst_local histogram -> hist2[k][N]
__global__ __launch_bounds__(BLK) void k_hist2(const int* __restrict__ packed,
                                               const int* __restrict__ ebstart,
                                               int N, int* __restrict__ hist2) {
  __shared__ int cnt[PART];
  for (int j = threadIdx.x; j < PART; j += BLK) cnt[j] = 0;
  __syncthreads();
  int b = blockIdx.x, k = blockIdx.y;
  int s0 = ebstart[b], len = ebstart[b + 1] - s0;
  int lo = s0 + (int)((long long)len * k / KB);
  int hi = s0 + (int)((long long)len * (k + 1) / KB);
  for (int i = lo + threadIdx.x; i < hi; i += BLK)
    atomicAdd(&cnt[packed[i] & (PART - 1)], 1);
  __syncthreads();
  int pstart = b << PSH;
  int psize = min(N - pstart, PART);
  int* out = hist2 + (size_t)k * N + pstart;
  for (int j = threadIdx.x; j < psize; j += BLK) out[j] = cnt[j];
}

// per-bucket scan: row_start[n] (global CSR offsets) + per-slice cursors
// (hist2 is rewritten IN PLACE into offs2)
__global__ __launch_bounds__(BLK) void k_scan2(int* __restrict__ hist2,
                                               const int* __restrict__ ebstart,
                                               int N, int* __restrict__ rs) {
  __shared__ int sc[PART];
  __shared__ int tsum[BLK];
  const int b = blockIdx.x, t = threadIdx.x;
  const int pstart = b << PSH;
  const int NPT = PART / BLK;  // 8 nodes per thread
  const int j0 = t * NPT;
  for (int u = 0; u < NPT; ++u) {
    int j = j0 + u, n = pstart + j, v = 0;
    if (n < N)
      for (int k = 0; k < KB; ++k) v += hist2[(size_t)k * N + n];
    sc[j] = v;
  }
  __syncthreads();
  int base = 0;
  for (int u = 0; u < NPT; ++u) base += sc[j0 + u];
  tsum[t] = base;
  __syncthreads();
  if (t == 0) {
    int run = 0;
    for (int q = 0; q < BLK; ++q) { int tmp = tsum[q]; tsum[q] = run; run += tmp; }
  }
  __syncthreads();
  int run = tsum[t] + ebstart[b];
  for (int u = 0; u < NPT; ++u) {
    int j = j0 + u, n = pstart + j;
    int c = sc[j];
    if (n < N) {
      rs[n] = run;
      int pos = run;
      for (int k = 0; k < KB; ++k) {
        int* p = &hist2[(size_t)k * N + n];
        int tmp = *p; *p = pos; pos += tmp;
      }
    }
    run += c;
  }
  if (b == gridDim.x - 1 && t == 0) rs[N] = ebstart[gridDim.x];
}

// scatter srcs into dst-sorted order using per-slice cursors
__global__ __launch_bounds__(BLK) void k_scatter2(const int* __restrict__ packed,
                                                  const int* __restrict__ offs2,
                                                  const int* __restrict__ ebstart,
                                                  int N, int* __restrict__ srcs) {
  __shared__ int cur[PART];
  int b = blockIdx.x, k = blockIdx.y;
  int pstart = b << PSH;
  for (int j = threadIdx.x; j < PART; j += BLK) {
    int n = pstart + j;
    cur[j] = (n < N) ? offs2[(size_t)k * N + n] : 0;
  }
  __syncthreads();
  int s0 = ebstart[b], len = ebstart[b + 1] - s0;
  int lo = s0 + (int)((long long)len * k / KB);
  int hi = s0 + (int)((long long)len * (k + 1) / KB);
  for (int i = lo + threadIdx.x; i < hi; i += BLK) {
    int e = packed[i];
    int p = atomicAdd(&cur[e & (PART - 1)], 1);
    srcs[p] = e >> PSH;
  }
}

// dinv from CSR degree; gx4 = (dinv*x, dinv)
__global__ void k_prepc(const int* __restrict__ rs, int N,
                        const float* __restrict__ x, float4* __restrict__ gx4) {
  int n = blockIdx.x * blockDim.x + threadIdx.x;
  if (n >= N) return;
  float di = rsqrtf((float)(rs[n + 1] - rs[n] + 1));  // +1 self-loop
  float4 g;
  g.x = di * x[3 * n + 0];
  g.y = di * x[3 * n + 1];
  g.z = di * x[3 * n + 2];
  g.w = di;
  gx4[n] = g;
}

// layer-1 segmented sum + fused W1+b1+relu+W2 -> g2 (no atomics)
__global__ void k_agg1(const int* __restrict__ rs, const int* __restrict__ srcs,
                       const float4* __restrict__ gx4,
                       const float* __restrict__ W1, const float* __restrict__ b1,
                       const float* __restrict__ W2, float* __restrict__ g2, int N) {
  int n = blockIdx.x * blockDim.x + threadIdx.x;
  if (n >= N) return;
  float4 g = gx4[n];
  float di = g.w;
  float a0 = g.x, a1 = g.y, a2 = g.z;  // self-loop term
  int lo = rs[n], hi = rs[n + 1];
  int i = lo;
  for (; i + 4 <= hi; i += 4) {
    int s0 = srcs[i], s1 = srcs[i + 1], s2 = srcs[i + 2], s3 = srcs[i + 3];
    float4 q0 = gx4[s0], q1 = gx4[s1], q2 = gx4[s2], q3 = gx4[s3];
    a0 += (q0.x + q1.x) + (q2.x + q3.x);
    a1 += (q0.y + q1.y) + (q2.y + q3.y);
    a2 += (q0.z + q1.z) + (q2.z + q3.z);
  }
  for (; i < hi; ++i) {
    float4 q = gx4[srcs[i]];
    a0 += q.x; a1 += q.y; a2 += q.z;
  }
  a0 *= di; a1 *= di; a2 *= di;
  float h2 = 0.0f;
#pragma unroll
  for (int k = 0; k < 16; ++k) {
    float o = fmaf(a0, W1[k], fmaf(a1, W1[16 + k], fmaf(a2, W1[32 + k], b1[k])));
    o = fmaxf(o, 0.0f);
    h2 = fmaf(o, W2[k], h2);
  }
  g2[n] = di * h2;
}

// layer-2 segmented sum + bias -> out (no atomics)
__global__ void k_agg2(const int* __restrict__ rs, const int* __restrict__ srcs,
                       const float* __restrict__ g2, const float4* __restrict__ gx4,
                       const float* __restrict__ b2, float* __restrict__ out, int N) {
  int n = blockIdx.x * blockDim.x + threadIdx.x;
  if (n >= N) return;
  float s = g2[n];  // self-loop
  int lo = rs[n], hi = rs[n + 1];
  int i = lo;
  for (; i + 8 <= hi; i += 8) {
    float t0 = g2[srcs[i + 0]], t1 = g2[srcs[i + 1]];
    float t2 = g2[srcs[i + 2]], t3 = g2[srcs[i + 3]];
    float t4 = g2[srcs[i + 4]], t5 = g2[srcs[i + 5]];
    float t6 = g2[srcs[i + 6]], t7 = g2[srcs[i + 7]];
    s += ((t0 + t1) + (t2 + t3)) + ((t4 + t5) + (t6 + t7));
  }
  for (; i < hi; ++i) s += g2[srcs[i]];
  out[n] = gx4[n].w * s + b2[0];
}

// ---------------- fallback (round-1 atomic) path ----------------

__global__ void k_zero(float* __restrict__ p, int n) {
  int i = blockIdx.x * blockDim.x + threadIdx.x;
  if (i < n) p[i] = 0.0f;
}

__global__ void k_deg(const void* __restrict__ idx, const int* __restrict__ flag,
                      int E, int* __restrict__ deg) {
  int i = blockIdx.x * blockDim.x + threadIdx.x;
  if (i >= E) return;
  int is64 = *flag;
  atomicAdd(&deg[edge_at(idx, is64, (long long)E + i)], 1);
}

__global__ void k_prep(const float* __restrict__ x, const int* __restrict__ deg,
                       float* __restrict__ dinv, float* __restrict__ gx, int N) {
  int n = blockIdx.x * blockDim.x + threadIdx.x;
  if (n >= N) return;
  float di = rsqrtf((float)(deg[n] + 1));
  dinv[n] = di;
  gx[3 * n + 0] = di * x[3 * n + 0];
  gx[3 * n + 1] = di * x[3 * n + 1];
  gx[3 * n + 2] = di * x[3 * n + 2];
}

__global__ void k_scat1(const void* __restrict__ idx, const int* __restrict__ flag,
                        int E, const float* __restrict__ gx, float* __restrict__ aggx) {
  int i = blockIdx.x * blockDim.x + threadIdx.x;
  if (i >= E) return;
  int is64 = *flag;
  int s = edge_at(idx, is64, i);
  int d = edge_at(idx, is64, (long long)E + i);
  unsafeAtomicAdd(&aggx[3 * d + 0], gx[3 * s + 0]);
  unsafeAtomicAdd(&aggx[3 * d + 1], gx[3 * s + 1]);
  unsafeAtomicAdd(&aggx[3 * d + 2], gx[3 * s + 2]);
}

__global__ void k_mid(const float* __restrict__ aggx, const float* __restrict__ gx,
                      const float* __restrict__ dinv,
                      const float* __restrict__ W1, const float* __restrict__ b1,
                      const float* __restrict__ W2, float* __restrict__ g2, int N) {
  int n = blockIdx.x * blockDim.x + threadIdx.x;
  if (n >= N) return;
  float di = dinv[n];
  float a0 = (aggx[3 * n + 0] + gx[3 * n + 0]) * di;
  float a1 = (aggx[3 * n + 1] + gx[3 * n + 1]) * di;
  float a2 = (aggx[3 * n + 2] + gx[3 * n + 2]) * di;
  float h2 = 0.0f;
#pragma unroll
  for (int k = 0; k < 16; ++k) {
    float o = fmaf(a0, W1[k], fmaf(a1, W1[16 + k], fmaf(a2, W1[32 + k], b1[k])));
    o = fmaxf(o, 0.0f);
    h2 = fmaf(o, W2[k], h2);
  }
  g2[n] = di * h2;
}

__global__ void k_scat2(const void* __restrict__ idx, const int* __restrict__ flag,
                        int E, const float* __restrict__ g2, float* __restrict__ agg2) {
  int i = blockIdx.x * blockDim.x + threadIdx.x;
  if (i >= E) return;
  int is64 = *flag;
  int s = edge_at(idx, is64, i);
  int d = edge_at(idx, is64, (long long)E + i);
  unsafeAtomicAdd(&agg2[d], g2[s]);
}

__global__ void k_final(const float* __restrict__ agg2, const float* __restrict__ g2,
                        const float* __restrict__ dinv, const float* __restrict__ b2,
                        float* __restrict__ out, int N) {
  int n = blockIdx.x * blockDim.x + threadIdx.x;
  if (n >= N) return;
  out[n] = dinv[n] * (agg2[n] + g2[n]) + b2[0];
}

// ---------------- launch ----------------

extern "C" void kernel_launch(void* const* d_in, const int* in_sizes, int n_in,
                              void* d_out, int out_size, void* d_ws, size_t ws_size,
                              hipStream_t stream) {
  const float* x  = (const float*)d_in[0];
  const void*  ei = d_in[1];
  const float* W1 = (const float*)d_in[2];
  const float* b1 = (const float*)d_in[3];
  const float* W2 = (const float*)d_in[4];
  const float* b2 = (const float*)d_in[5];
  float* out = (float*)d_out;

  const int N = in_sizes[0] / 3;   // 200000
  const int E = in_sizes[1] / 2;   // 6400000
  const int NB = (N + PART - 1) >> PSH;  // 98

  char* ws = (char*)d_ws;
  int gN = (N + BLK - 1) / BLK;
  int gE = (E + BLK - 1) / BLK;

  // CSR-path layout (256B-aligned cursor)
  size_t cur = 0;
  auto take = [&](size_t bytes) { size_t o = cur; cur += (bytes + 255) & ~(size_t)255; return (void*)(ws + o); };
  int* flag    = (int*)take(256);
  int* ebstart = (int*)take((size_t)(MAXB + 1) * 4);
  int* hist    = (int*)take((size_t)NB * G1 * 4);        // scanned in place -> offs
  int* packed  = (int*)take((size_t)E * 4);
  int* srcs    = (int*)take((size_t)E * 4);
  int* rs      = (int*)take((size_t)(N + 1) * 4);
  // region B: offs2/hist2 [KB][N] ints, later overlaid by gx4[N] + g2[N]
  size_t regB = (size_t)KB * N * 4;
  size_t regB2 = (size_t)N * 16 + 256 + (size_t)N * 4;
  char* Bbase = (char*)take(regB > regB2 ? regB : regB2);
  int*    hist2 = (int*)Bbase;                 // [KB][N], becomes offs2 in place
  float4* gx4   = (float4*)Bbase;              // written after scatter2
  float*  g2    = (float*)(Bbase + (((size_t)N * 16 + 255) & ~(size_t)255));
  size_t need = cur;

  if (ws_size >= need && NB <= MAXB && N <= (1 << 19)) {
    int chunk = (E + G1 - 1) / G1;
    k_detect<<<1, 256, 0, stream>>>((const unsigned*)ei, flag);
    k_hist<<<G1, BLK, 0, stream>>>(ei, flag, E, chunk, NB, hist);
    k_scan<<<1, MAXB, 0, stream>>>(hist, NB, ebstart);
    k_part<<<G1, BLK, 0, stream>>>(ei, flag, E, chunk, NB, hist, ebstart, packed);
    k_hist2<<<dim3(NB, KB), BLK, 0, stream>>>(packed, ebstart, N, hist2);
    k_scan2<<<NB, BLK, 0, stream>>>(hist2, ebstart, N, rs);
    k_scatter2<<<dim3(NB, KB), BLK, 0, stream>>>(packed, hist2, ebstart, N, srcs);
    k_prepc<<<gN, BLK, 0, stream>>>(rs, N, x, gx4);
    k_agg1<<<gN, BLK, 0, stream>>>(rs, srcs, gx4, W1, b1, W2, g2, N);
    k_agg2<<<gN, BLK, 0, stream>>>(rs, srcs, g2, gx4, b2, out, N);
  } else {
    // round-1 fallback
    int*   deg   = (int*)(ws + 256);
    float* aggx  = (float*)(ws + 256 + 4ll * N);
    float* agg2b = (float*)(ws + 256 + 4ll * N * 4);
    float* dinvf = (float*)(ws + 256 + 4ll * N * 5);
    float* gx    = (float*)(ws + 256 + 4ll * N * 6);
    float* g2f   = (float*)(ws + 256 + 4ll * N * 9);

    int gZ = (5 * N + BLK - 1) / BLK;

    k_detect<<<1, 256, 0, stream>>>((const unsigned*)ei, (int*)ws);
    k_zero<<<gZ, BLK, 0, stream>>>((float*)deg, 5 * N);
    k_deg<<<gE, BLK, 0, stream>>>(ei, (int*)ws, E, deg);
    k_prep<<<gN, BLK, 0, stream>>>(x, deg, dinvf, gx, N);
    k_scat1<<<gE, BLK, 0, stream>>>(ei, (int*)ws, E, gx, aggx);
    k_mid<<<gN, BLK, 0, stream>>>(aggx, gx, dinvf, W1, b1, W2, g2f, N);
    k_scat2<<<gE, BLK, 0, stream>>>(ei, (int*)ws, E, g2f, agg2b);
    k_final<<<gN, BLK, 0, stream>>>(agg2b, g2f, dinvf, b2, out, N);
  }
}